// Round 8
// baseline (205.618 us; speedup 1.0000x reference)
//
#include <hip/hip_runtime.h>
#include <math.h>

// Problem constants (fixed by the reference).
constexpr int B_ROWS = 32768;
constexpr int C_COLS = 1000;
constexpr int VEC4   = C_COLS / 4;   // 250 float4 per row; row base = 4000 B -> 16B aligned
constexpr int NBLK   = 2048;         // persistent blocks: 8/CU x 256 CUs, all resident
constexpr int RPB    = B_ROWS / NBLK; // 16 rows per block

using f4 = __attribute__((ext_vector_type(4))) float;

// Persistent block-per-row pipeline:
//  - 2048 blocks x 256 threads, one float4 of x and lams[t] per thread.
//  - Each block processes 16 rows (row = blockIdx + i*2048) with a 2-deep
//    register prefetch of {target, x} for row i+1 issued BEFORE row i's
//    reduction. hipcc's mandatory vmcnt(0) drain at __syncthreads then
//    completes the prefetch exactly when it's about to be consumed.
//  - ONE barrier per row: wave-local (m_w, s_w, dot_w, rs_w) via shfl
//    butterfly -> LDS -> barrier -> all threads merge the 4 wave stats with
//    the online-softmax rule s = sum_w s_w * exp(m_w - m).
//  - LDS stats are double-buffered (iteration parity) so no 2nd barrier is
//    needed: the next write to buffer cb is fenced by barrier i+1.
__global__ __launch_bounds__(256, 8) void ols_main(
    const float* __restrict__ output,   // [B, C]
    const int*   __restrict__ target,   // [B]
    const float* __restrict__ lams,     // [C, C]
    float*       __restrict__ partials, // [NBLK] (d_ws)
    float*       __restrict__ lams_upd, // [C, C]
    float*       __restrict__ cnt_upd)  // [C]
{
    __shared__ float s_stat[2][4][4];   // [buf][wave][m,s,dot,rs]
    __shared__ float s_xt[2];

    const int tid  = threadIdx.x;
    const int lane = tid & 63;
    const int wid  = tid >> 6;
    const bool act = tid < VEC4;        // threads 250..255 idle-pad

    const f4 X_PAD = (f4){-INFINITY, -INFINITY, -INFINITY, -INFINITY};

    float lossAcc = 0.0f;

    // ---- prologue: load row 0 ----
    int tb[2];
    f4  xb[2];
    tb[0] = target[blockIdx.x];
    xb[0] = act ? reinterpret_cast<const f4*>(output + (size_t)blockIdx.x * C_COLS)[tid]
                : X_PAD;

#pragma unroll
    for (int i = 0; i < RPB; ++i) {
        const int cb = i & 1, nb = cb ^ 1;   // compile-time after unroll

        // ---- prefetch next row's {target, x} (consumed after the barrier) ----
        if (i + 1 < RPB) {
            const int nrow = blockIdx.x + (i + 1) * NBLK;
            tb[nb] = target[nrow];
            xb[nb] = act ? reinterpret_cast<const f4*>(output + (size_t)nrow * C_COLS)[tid]
                         : X_PAD;
        }

        const int t = tb[cb];                // block-uniform
        const f4  x = xb[cb];

        // lams row (4 MB table, L2-resident): issued now, consumed ~200 cy
        // later in the dot butterfly.
        const f4 l = act ? reinterpret_cast<const f4*>(lams + (size_t)t * C_COLS)[tid]
                         : (f4){0.0f, 0.0f, 0.0f, 0.0f};

        // ---- wave-local max ----
        float mw = fmaxf(fmaxf(x[0], x[1]), fmaxf(x[2], x[3]));
#pragma unroll
        for (int off = 32; off > 0; off >>= 1) mw = fmaxf(mw, __shfl_xor(mw, off));

        // ---- exp against the WAVE max (kept live for the scatter) ----
        const float p0 = __expf(x[0] - mw), p1 = __expf(x[1] - mw);
        const float p2 = __expf(x[2] - mw), p3 = __expf(x[3] - mw);
        float s = (p0 + p1) + (p2 + p3);     // -INF pads give 0
        // dot guarded: pads have l=0, x=-INF and 0*(-inf)=NaN (round-5 bug).
        float dot = act ? (l[0]*x[0] + l[1]*x[1]) + (l[2]*x[2] + l[3]*x[3]) : 0.0f;
        float rs  = (l[0] + l[1]) + (l[2] + l[3]);
#pragma unroll
        for (int off = 32; off > 0; off >>= 1) {
            s   += __shfl_xor(s,   off);
            dot += __shfl_xor(dot, off);
            rs  += __shfl_xor(rs,  off);
        }
        if (lane == 0) {
            s_stat[cb][wid][0] = mw; s_stat[cb][wid][1] = s;
            s_stat[cb][wid][2] = dot; s_stat[cb][wid][3] = rs;
        }
        // capture x[t] (t = 4*q + e; thread q holds it)
        if (tid == (t >> 2)) {
            const int e = t & 3;
            s_xt[cb] = (e == 0) ? x[0] : (e == 1) ? x[1] : (e == 2) ? x[2] : x[3];
        }
        __syncthreads();   // also completes the row-(i+1) prefetch (vmcnt drain)

        // ---- merge the 4 wave stats (online-softmax rule) ----
        const float m0 = s_stat[cb][0][0], m1 = s_stat[cb][1][0];
        const float m2 = s_stat[cb][2][0], m3 = s_stat[cb][3][0];
        const float m  = fmaxf(fmaxf(m0, m1), fmaxf(m2, m3));
        const float S  = s_stat[cb][0][1] * __expf(m0 - m)
                       + s_stat[cb][1][1] * __expf(m1 - m)
                       + s_stat[cb][2][1] * __expf(m2 - m)
                       + s_stat[cb][3][1] * __expf(m3 - m);
        const float x_t = s_xt[cb];

        if (tid == 0) {
            const float D = (s_stat[cb][0][2] + s_stat[cb][1][2])
                          + (s_stat[cb][2][2] + s_stat[cb][3][2]);
            const float R = (s_stat[cb][0][3] + s_stat[cb][1][3])
                          + (s_stat[cb][2][3] + s_stat[cb][3][3]);
            const float lse = m + __logf(S);
            // 0.5*(lse - x_t) [hard CE] + 0.5*(lse*rowsum - dot) [soft CE]
            lossAcc += 0.5f * ((lse - x_t) + (lse * R - D));
        }

        // ---- update_loss_lams: argmax==target <=> x[t]==rowmax (unique max) ----
        if (x_t == m) {                      // block-uniform, ~B/C rows total
            const float scale = __expf(s_stat[cb][wid][0] - m) / S;
            if (act) {
                float* dst = lams_upd + (size_t)t * C_COLS + 4 * tid;
                atomicAdd(dst + 0, p0 * scale);
                atomicAdd(dst + 1, p1 * scale);
                atomicAdd(dst + 2, p2 * scale);
                atomicAdd(dst + 3, p3 * scale);
            }
            if (tid == 0) atomicAdd(&cnt_upd[t], 1.0f);
        }
        // no trailing barrier: next iteration writes s_stat[nb]/s_xt[nb]; the
        // next write to THIS buffer is fenced by barrier i+1.
    }

    if (tid == 0) partials[blockIdx.x] = lossAcc;
}

// Single-block reducer: 2048 partials -> d_loss. 256 threads x 2 float4.
__global__ __launch_bounds__(256) void ols_reduce(
    const float* __restrict__ partials, float* __restrict__ d_loss)
{
    __shared__ float sm[4];
    const int lane = threadIdx.x & 63;
    const int wid  = threadIdx.x >> 6;
    const f4* p4 = reinterpret_cast<const f4*>(partials);   // 512 float4
    f4 a = p4[threadIdx.x];
    f4 b = p4[threadIdx.x + 256];
    float acc = ((a[0] + a[1]) + (a[2] + a[3])) + ((b[0] + b[1]) + (b[2] + b[3]));
#pragma unroll
    for (int off = 32; off > 0; off >>= 1) acc += __shfl_xor(acc, off);
    if (lane == 0) sm[wid] = acc;
    __syncthreads();
    if (threadIdx.x == 0)
        *d_loss = ((sm[0] + sm[1]) + (sm[2] + sm[3])) * (1.0f / (float)B_ROWS);
}

extern "C" void kernel_launch(void* const* d_in, const int* in_sizes, int n_in,
                              void* d_out, int out_size, void* d_ws, size_t ws_size,
                              hipStream_t stream) {
    const float* output = (const float*)d_in[0];   // [B, C] f32
    const int*   target = (const int*)d_in[1];     // [B] int
    const float* lams   = (const float*)d_in[2];   // [C, C] f32

    float* out      = (float*)d_out;
    float* d_loss   = out;                          // [1]
    float* lams_upd = out + 1;                      // [C, C]
    float* cnt_upd  = out + 1 + C_COLS * C_COLS;    // [C]
    float* partials = (float*)d_ws;                 // [NBLK] = 8 KB

    // d_out is poisoned 0xAA before every timed launch; lams_upd/cnt_upd are
    // accumulated via atomics, so zero-init (async memset is capture-safe).
    hipMemsetAsync(d_out, 0, (size_t)out_size * sizeof(float), stream);

    ols_main<<<dim3(NBLK), dim3(256), 0, stream>>>(output, target, lams,
                                                   partials, lams_upd, cnt_upd);
    ols_reduce<<<dim3(1), dim3(256), 0, stream>>>(partials, d_loss);
}